// Round 1
// baseline (464.032 us; speedup 1.0000x reference)
//
#include <hip/hip_runtime.h>

#define LD 4800
#define SD 4800
#define CD 256
#define H0 60
#define W0 80
#define NBATCH 2
#define THRV 0.2f
#define NEGINF (-1000000000.0f)
#define SIMSCALE 0.0390625f   // (1/sqrt(256))^2 / 0.1

typedef __attribute__((ext_vector_type(8))) short bf16x8;
typedef __attribute__((ext_vector_type(4))) float f32x4;
typedef __attribute__((ext_vector_type(4))) unsigned short u16x4;

// ---- mask helpers: auto-detect storage dtype (u8 bool vs 4-byte) ----
// mask0[0,0,1] is True (batch 0 is full-frame). If stored as 1-byte bool,
// byte[1] != 0. If stored as int32/float32, byte[1] is the 2nd byte of
// element 0 -> 0. For 4-byte elements, "nonzero word" = True (covers both
// int32 1 and float32 1.0f).
__device__ __forceinline__ bool mask_is_u8(const void* m) {
  return ((const unsigned char*)m)[1] != 0;
}
__device__ __forceinline__ bool mask_at(const void* m, int idx, bool u8) {
  if (u8) return ((const unsigned char*)m)[idx] != 0;
  return ((const unsigned int*)m)[idx] != 0u;
}
__device__ __forceinline__ unsigned short f2bf(float x) {
  // round-half-up bf16 conversion (magnitude rounding; inputs are finite)
  return (unsigned short)((__float_as_uint(x) + 0x8000u) >> 16);
}

// ---- workspace layout (bytes) ----
// rowsum  f32[NB*LD]   @ 0       (38400 B)
// colsum  f32[NB*SD]   @ 38400   (38400 B)
// colmax  u32[NB*SD]   @ 76800   (38400 B)
// rowbest u64[NB*LD]   @ 115200  (76800 B)
// dims    i32[8]       @ 192000  (hs0[2], ws0[2], hs1[2], ws1[2])

__global__ void init_kernel(const void* __restrict__ m0, const void* __restrict__ m1,
                            unsigned* __restrict__ wszero, int* __restrict__ dims) {
  const int t = threadIdx.x;
  const int gid = blockIdx.x * 256 + t;
  // zero rowsum+colsum+colmax+rowbest = 192000 bytes = 48000 words
  for (int i = gid; i < 48000; i += gridDim.x * 256) wszero[i] = 0u;
  if (blockIdx.x != 0) return;

  const bool u8 = mask_is_u8(m0);
  __shared__ short cnt[160];
  // mask0 column sums -> hs0 = max_w sum_h
  if (t < NBATCH * W0) {
    int n = t / W0, w = t % W0, c = 0;
    for (int h = 0; h < H0; ++h) c += mask_at(m0, n * LD + h * W0 + w, u8) ? 1 : 0;
    cnt[t] = (short)c;
  }
  __syncthreads();
  if (t < NBATCH) { int mx = 0; for (int w = 0; w < W0; ++w) mx = max(mx, (int)cnt[t * W0 + w]); dims[0 + t] = mx; }
  __syncthreads();
  // mask0 row sums -> ws0 = max_h sum_w
  if (t < NBATCH * H0) {
    int n = t / H0, h = t % H0, c = 0;
    for (int w = 0; w < W0; ++w) c += mask_at(m0, n * LD + h * W0 + w, u8) ? 1 : 0;
    cnt[t] = (short)c;
  }
  __syncthreads();
  if (t < NBATCH) { int mx = 0; for (int h = 0; h < H0; ++h) mx = max(mx, (int)cnt[t * H0 + h]); dims[2 + t] = mx; }
  __syncthreads();
  // mask1 column sums -> hs1
  if (t < NBATCH * W0) {
    int n = t / W0, w = t % W0, c = 0;
    for (int h = 0; h < H0; ++h) c += mask_at(m1, n * SD + h * W0 + w, u8) ? 1 : 0;
    cnt[t] = (short)c;
  }
  __syncthreads();
  if (t < NBATCH) { int mx = 0; for (int w = 0; w < W0; ++w) mx = max(mx, (int)cnt[t * W0 + w]); dims[4 + t] = mx; }
  __syncthreads();
  // mask1 row sums -> ws1
  if (t < NBATCH * H0) {
    int n = t / H0, h = t % H0, c = 0;
    for (int w = 0; w < W0; ++w) c += mask_at(m1, n * SD + h * W0 + w, u8) ? 1 : 0;
    cnt[t] = (short)c;
  }
  __syncthreads();
  if (t < NBATCH) { int mx = 0; for (int h = 0; h < H0; ++h) mx = max(mx, (int)cnt[t * H0 + h]); dims[6 + t] = mx; }
}

// Pass A: bf16 MFMA GEMM -> masked sim written to conf region of d_out,
// fused exp-row-sums / exp-col-sums via atomics.
__global__ __launch_bounds__(256)
void gemm_kernel(const float* __restrict__ f0, const float* __restrict__ f1,
                 const void* __restrict__ m0, const void* __restrict__ m1,
                 float* __restrict__ simout, float* __restrict__ rowsum,
                 float* __restrict__ colsum) {
  const int n  = blockIdx.z;
  const int br = blockIdx.y * 128;   // row tile origin (L)
  const int bs = blockIdx.x * 128;   // col tile origin (S)
  const int t = threadIdx.x;
  const int lane = t & 63, wv = t >> 6;
  const int wr = wv >> 1, wc = wv & 1;
  const int q = lane >> 4, c0 = lane & 15;

  // padded to 40 bf16/row (80 B): 16B-aligned rows, bank-stride 20 -> ~2-way (free)
  __shared__ unsigned short As[128 * 40];
  __shared__ unsigned short Bs[128 * 40];

  const float* A = f0 + (size_t)n * LD * CD;
  const float* B = f1 + (size_t)n * SD * CD;

  f32x4 acc[4][4] = {};

  for (int k0 = 0; k0 < CD; k0 += 32) {
    __syncthreads();
#pragma unroll
    for (int i = 0; i < 4; ++i) {
      int e = (i * 256 + t) * 4;           // 0..4092
      int row = e >> 5, k = e & 31;
      int gr = br + row; if (gr >= LD) gr = LD - 1;
      int gs = bs + row; if (gs >= SD) gs = SD - 1;
      f32x4 va = *(const f32x4*)(A + (size_t)gr * CD + (k0 + k));
      f32x4 vb = *(const f32x4*)(B + (size_t)gs * CD + (k0 + k));
      u16x4 ua = { f2bf(va.x), f2bf(va.y), f2bf(va.z), f2bf(va.w) };
      u16x4 ub = { f2bf(vb.x), f2bf(vb.y), f2bf(vb.z), f2bf(vb.w) };
      *(u16x4*)(As + row * 40 + k) = ua;
      *(u16x4*)(Bs + row * 40 + k) = ub;
    }
    __syncthreads();
    bf16x8 af[4], bfr[4];
#pragma unroll
    for (int m = 0; m < 4; ++m)
      af[m] = *(const bf16x8*)(As + (wr * 64 + m * 16 + c0) * 40 + q * 8);
#pragma unroll
    for (int m = 0; m < 4; ++m)
      bfr[m] = *(const bf16x8*)(Bs + (wc * 64 + m * 16 + c0) * 40 + q * 8);
#pragma unroll
    for (int m = 0; m < 4; ++m)
#pragma unroll
      for (int nn = 0; nn < 4; ++nn)
        acc[m][nn] = __builtin_amdgcn_mfma_f32_16x16x32_bf16(af[m], bfr[nn], acc[m][nn], 0, 0, 0);
  }

  // ---- epilogue: mask, store sim, exp partial sums ----
  const bool u8 = mask_is_u8(m0);
  int grow[16]; bool inrow[16], mrow[16];
#pragma unroll
  for (int m = 0; m < 4; ++m)
#pragma unroll
    for (int i = 0; i < 4; ++i) {
      int r = br + wr * 64 + m * 16 + q * 4 + i;
      int idx = m * 4 + i;
      grow[idx] = r;
      bool inb = r < LD;
      inrow[idx] = inb;
      mrow[idx] = inb && mask_at(m0, n * LD + (inb ? r : 0), u8);
    }
  int gcol[4]; bool incol[4], mcol[4];
#pragma unroll
  for (int nn = 0; nn < 4; ++nn) {
    int c = bs + wc * 64 + nn * 16 + c0;
    gcol[nn] = c;
    bool inb = c < SD;
    incol[nn] = inb;
    mcol[nn] = inb && mask_at(m1, n * SD + (inb ? c : 0), u8);
  }

  float rpart[16];
#pragma unroll
  for (int i = 0; i < 16; ++i) rpart[i] = 0.f;
  float cpart[4] = {0.f, 0.f, 0.f, 0.f};

#pragma unroll
  for (int m = 0; m < 4; ++m)
#pragma unroll
    for (int nn = 0; nn < 4; ++nn) {
      f32x4 a = acc[m][nn];
#pragma unroll
      for (int i = 0; i < 4; ++i) {
        int idx = m * 4 + i;
        float val = a[i] * SIMSCALE;
        bool v = mrow[idx] && mcol[nn];
        float e = v ? __expf(val) : 0.f;
        rpart[idx] += e;
        cpart[nn] += e;
        if (inrow[idx] && incol[nn])
          simout[((size_t)n * LD + grow[idx]) * SD + gcol[nn]] = v ? val : NEGINF;
      }
    }

#pragma unroll
  for (int idx = 0; idx < 16; ++idx) {
    float s = rpart[idx];
    s += __shfl_xor(s, 1); s += __shfl_xor(s, 2);
    s += __shfl_xor(s, 4); s += __shfl_xor(s, 8);
    if (c0 == 0 && inrow[idx]) atomicAdd(&rowsum[n * LD + grow[idx]], s);
  }
#pragma unroll
  for (int nn = 0; nn < 4; ++nn) {
    float s = cpart[nn];
    s += __shfl_xor(s, 16); s += __shfl_xor(s, 32);
    if (q == 0 && incol[nn]) atomicAdd(&colsum[n * SD + gcol[nn]], s);
  }
}

// Pass B: sim -> conf in place; track per-row (max,argmax) and per-col max.
__global__ __launch_bounds__(256)
void conf_kernel(float* __restrict__ buf, const float* __restrict__ rowsum,
                 const float* __restrict__ colsum,
                 const void* __restrict__ m0, const void* __restrict__ m1,
                 unsigned* __restrict__ colmax, unsigned long long* __restrict__ rowbest) {
  const int n  = blockIdx.z;
  const int ro = blockIdx.x * 64;
  const int co = blockIdx.y * 256;
  const int t = threadIdx.x, lane = t & 63, wv = t >> 6;
  const bool u8 = mask_is_u8(m0);
  const int c = co + lane * 4;
  const bool colok = c < SD;          // tiles are 4-col granular (4800 % 4 == 0)
  const float invS = 1.0f / SD, invL = 1.0f / LD;

  f32x4 cinv = {0.f, 0.f, 0.f, 0.f};
  bool mc1v[4] = {false, false, false, false};
  if (colok) {
    f32x4 cs = *(const f32x4*)(colsum + n * SD + c);
    cinv.x = 1.0f / cs.x; cinv.y = 1.0f / cs.y;
    cinv.z = 1.0f / cs.z; cinv.w = 1.0f / cs.w;
#pragma unroll
    for (int j = 0; j < 4; ++j) mc1v[j] = mask_at(m1, n * SD + c + j, u8);
  }
  float cm[4] = {0.f, 0.f, 0.f, 0.f};

  for (int i = 0; i < 16; ++i) {
    const int r = ro + i * 4 + wv;
    const float rinv = 1.0f / rowsum[n * LD + r];   // inf for masked rows: dead branch
    const bool mc0r = mask_at(m0, n * LD + r, u8);
    unsigned long long key = 0ull;
    if (colok) {
      size_t off = ((size_t)n * LD + r) * SD + c;
      f32x4 sv = *(f32x4*)(buf + off);
      f32x4 cf;
      float best = -1.f; int bc = c;
#pragma unroll
      for (int j = 0; j < 4; ++j) {
        float e = __expf(sv[j]);                    // exp(-1e9) -> 0
        float Aa = mc0r   ? e * rinv   : invS;      // softmax over axis 2
        float Bb = mc1v[j] ? e * cinv[j] : invL;    // softmax over axis 1
        float cv = Aa * Bb;
        cf[j] = cv;
        if (cv > best) { best = cv; bc = c + j; }   // first-index tiebreak
        cm[j] = fmaxf(cm[j], cv);
      }
      *(f32x4*)(buf + off) = cf;
      key = ((unsigned long long)__float_as_uint(best) << 32) | (unsigned)(~bc);
    }
#pragma unroll
    for (int d = 1; d < 64; d <<= 1) {
      unsigned long long ok = __shfl_xor(key, d);
      key = (ok > key) ? ok : key;
    }
    if (lane == 0) atomicMax(&rowbest[n * LD + r], key);
  }

  __shared__ unsigned shm[4][256];
#pragma unroll
  for (int j = 0; j < 4; ++j) shm[wv][lane * 4 + j] = colok ? __float_as_uint(cm[j]) : 0u;
  __syncthreads();
  {
    unsigned mx = max(max(shm[0][t], shm[1][t]), max(shm[2][t], shm[3][t]));
    int cc = co + t;
    if (cc < SD) atomicMax(&colmax[n * SD + cc], mx);
  }
}

// Pass C: match extraction (mask_v, j_ids, mconf, mkpts0, mkpts1)
__global__ void final_kernel(const unsigned long long* __restrict__ rowbest,
                             const unsigned* __restrict__ colmax,
                             const int* __restrict__ dims,
                             float* __restrict__ out) {
  const int n = blockIdx.y;
  const int l = blockIdx.x * 256 + threadIdx.x;
  if (l >= LD) return;
  unsigned long long key = rowbest[(size_t)n * LD + l];
  float rmax = __uint_as_float((unsigned)(key >> 32));
  int j = (int)(~(unsigned)(key & 0xFFFFFFFFull));
  if (j < 0 || j >= SD) j = 0;
  const int hs0 = dims[0 + n], ws0 = dims[2 + n], hs1 = dims[4 + n], ws1 = dims[6 + n];
  const int h = l / W0, w = l % W0;
  const bool v0 = (h >= 2) && (h < hs0 - 2) && (w >= 2) && (w < ws0 - 2);
  const int jh = j / W0, jw = j % W0;
  const bool v1 = (jh >= 2) && (jh < hs1 - 2) && (jw >= 2) && (jw < ws1 - 2);
  const float cmx = __uint_as_float(colmax[(size_t)n * SD + j]);
  const bool mv = (rmax > THRV) && v0 && v1 && (rmax == cmx);
  const int jid = mv ? j : 0;

  const size_t base = (size_t)NBATCH * LD * SD;
  const int NL = NBATCH * LD;
  out[base + (size_t)n * LD + l]            = mv ? 1.f : 0.f;          // mask_v
  out[base + NL + (size_t)n * LD + l]       = (float)jid;              // j_ids
  out[base + 2 * (size_t)NL + (size_t)n * LD + l] = mv ? rmax : 0.f;   // mconf
  size_t mk0 = base + 3 * (size_t)NL + ((size_t)n * LD + l) * 2;
  out[mk0 + 0] = (float)(w * 8);
  out[mk0 + 1] = (float)(h * 8);
  size_t mk1 = base + 5 * (size_t)NL + ((size_t)n * LD + l) * 2;
  out[mk1 + 0] = (float)((jid % W0) * 8);
  out[mk1 + 1] = (float)((jid / W0) * 8);
}

extern "C" void kernel_launch(void* const* d_in, const int* in_sizes, int n_in,
                              void* d_out, int out_size, void* d_ws, size_t ws_size,
                              hipStream_t stream) {
  (void)in_sizes; (void)n_in; (void)out_size; (void)ws_size;
  const float* f0 = (const float*)d_in[0];
  const float* f1 = (const float*)d_in[1];
  const void*  m0 = d_in[2];
  const void*  m1 = d_in[3];
  float* out = (float*)d_out;
  char* ws = (char*)d_ws;

  float* rowsum = (float*)(ws);
  float* colsum = (float*)(ws + 38400);
  unsigned* colmax = (unsigned*)(ws + 76800);
  unsigned long long* rowbest = (unsigned long long*)(ws + 115200);
  int* dims = (int*)(ws + 192000);

  init_kernel<<<64, 256, 0, stream>>>(m0, m1, (unsigned*)ws, dims);
  gemm_kernel<<<dim3(38, 38, 2), 256, 0, stream>>>(f0, f1, m0, m1, out, rowsum, colsum);
  conf_kernel<<<dim3(75, 19, 2), 256, 0, stream>>>(out, rowsum, colsum, m0, m1, colmax, rowbest);
  final_kernel<<<dim3(19, 2), 256, 0, stream>>>(rowbest, colmax, dims, out);
}

// Round 6
// 419.073 us; speedup vs baseline: 1.1073x; 1.1073x over previous
//
#include <hip/hip_runtime.h>

#define LD 4800
#define SD 4800
#define CD 256
#define H0 60
#define W0 80
#define NB 2
#define THRV 0.2f
#define SIMSCALE 0.0390625f   // (1/sqrt(256))^2 / 0.1
#define INVL (1.0f/4800.0f)   // == 1/S as well

typedef __attribute__((ext_vector_type(8))) short bf16x8;
typedef __attribute__((ext_vector_type(4))) float f32x4;
typedef __attribute__((ext_vector_type(4))) unsigned short u16x4;
typedef __attribute__((ext_vector_type(8))) unsigned short u16x8;
typedef unsigned long long ull;

// ---- mask helpers: auto-detect storage dtype (u8 bool vs 4-byte) ----
__device__ __forceinline__ bool mask_is_u8(const void* m) {
  return ((const unsigned char*)m)[1] != 0;   // mask0[0,0,1] is True
}
__device__ __forceinline__ bool mask_at(const void* m, int idx, bool u8) {
  return u8 ? (((const unsigned char*)m)[idx] != 0)
            : (((const unsigned int*)m)[idx] != 0u);
}
__device__ __forceinline__ unsigned short f2bf(float x) {
  return (unsigned short)((__float_as_uint(x) + 0x8000u) >> 16);
}

// ---- workspace layout (GLL path) ----
// fb0 bf16[2*4800*256]  @ 0          (4,915,200 B)
// fb1 bf16[2*4800*256]  @ 4,915,200  (4,915,200 B)
// sums base             @ 9,830,400:
//   rowsum  f32[9600]   +0
//   colsum  f32[9600]   +38400
//   colmax  u32[9600]   +76800
//   rowbest u64[9600]   +115200
//   dims    i32[8]      +192000
// fallback (small ws): sums base @ 0, no fb.

__global__ __launch_bounds__(256)
void prep_kernel(const float* __restrict__ f0, const float* __restrict__ f1,
                 const void* __restrict__ m0, const void* __restrict__ m1,
                 unsigned short* __restrict__ fb0, unsigned short* __restrict__ fb1,
                 unsigned* __restrict__ zws, int* __restrict__ dims, int do_conv) {
  const int t = threadIdx.x;
  const int gid = blockIdx.x * 256 + t;
  const int stride = gridDim.x * 256;
  // zero sums region: rowsum+colsum+colmax+rowbest = 192000 B = 48000 words
  for (int i = gid; i < 48000; i += stride) zws[i] = 0u;
  // convert features f32 -> bf16 (8 elems / iter)
  if (do_conv) {
    for (int g = gid; g < 614400; g += stride) {
      int gg = g; const float* src; unsigned short* dst;
      if (gg < 307200) { src = f0; dst = fb0; } else { gg -= 307200; src = f1; dst = fb1; }
      size_t off = (size_t)gg * 8;
      f32x4 a = *(const f32x4*)(src + off);
      f32x4 b = *(const f32x4*)(src + off + 4);
      u16x8 o = { f2bf(a.x), f2bf(a.y), f2bf(a.z), f2bf(a.w),
                  f2bf(b.x), f2bf(b.y), f2bf(b.z), f2bf(b.w) };
      *(u16x8*)(dst + off) = o;
    }
  }
  // mask effective dims, one section per block 0..3
  if (blockIdx.x < 4) {
    const bool u8 = mask_is_u8(m0);
    __shared__ short cnt[160];
    const int s = blockIdx.x;
    const void* mm = (s < 2) ? m0 : m1;
    if (s == 0 || s == 2) {          // hs = max_w sum_h
      if (t < NB * W0) {
        int n = t / W0, w = t % W0, c = 0;
        for (int h = 0; h < H0; ++h) c += mask_at(mm, n * LD + h * W0 + w, u8) ? 1 : 0;
        cnt[t] = (short)c;
      }
      __syncthreads();
      if (t < NB) {
        int mx = 0;
        for (int w = 0; w < W0; ++w) mx = max(mx, (int)cnt[t * W0 + w]);
        dims[(s == 0 ? 0 : 4) + t] = mx;
      }
    } else {                         // ws = max_h sum_w
      if (t < NB * H0) {
        int n = t / H0, h = t % H0, c = 0;
        for (int w = 0; w < W0; ++w) c += mask_at(mm, n * LD + h * W0 + w, u8) ? 1 : 0;
        cnt[t] = (short)c;
      }
      __syncthreads();
      if (t < NB) {
        int mx = 0;
        for (int h = 0; h < H0; ++h) mx = max(mx, (int)cnt[t * H0 + h]);
        dims[(s == 1 ? 2 : 6) + t] = mx;
      }
    }
  }
}

// PASS 0: GEMM + exp row/col sums (no matrix store).
// PASS 1: GEMM + conf write + row (max,argmax) / col max tracking.
// GLL 1: bf16 features staged via global_load_lds (wave-uniform LDS dest).
// GLL 0: fallback, f32 load + in-kernel convert + ds_write.
template<int PASS, int GLL>
__global__ __launch_bounds__(256)
void gemm_fused(const unsigned short* __restrict__ fb0,
                const unsigned short* __restrict__ fb1,
                const float* __restrict__ f0, const float* __restrict__ f1,
                const void* __restrict__ m0, const void* __restrict__ m1,
                float* __restrict__ out, float* __restrict__ rowsum,
                float* __restrict__ colsum, unsigned* __restrict__ colmax,
                ull* __restrict__ rowbest) {
  const int n  = blockIdx.z;
  const int br = blockIdx.y * 128;
  const int bs = blockIdx.x * 128;
  const int t = threadIdx.x;
  const int lane = t & 63, wv = t >> 6;
  const int wr = wv >> 1, wc = wv & 1;
  const int q = lane >> 4, c0 = lane & 15;

  __shared__ unsigned short As[128 * 32];   // linear, rows of 64 B
  __shared__ unsigned short Bs[128 * 32];

  f32x4 acc[4][4] = {};

  if constexpr (GLL) {
    const unsigned short* Ab = fb0 + (size_t)n * LD * CD;
    const unsigned short* Bb = fb1 + (size_t)n * SD * CD;
    const int kk = (t & 3) * 8;              // k sub-offset (8 bf16 = 16 B)
    const int r0 = t >> 2;                   // rows 0..63 (j=0), +64 (j=1)
    const int gr0 = min(br + r0, LD - 1),      gs0 = min(bs + r0, SD - 1);
    const int gr1 = min(br + r0 + 64, LD - 1), gs1 = min(bs + r0 + 64, SD - 1);
    for (int k0 = 0; k0 < CD; k0 += 32) {
      __syncthreads();
      __builtin_amdgcn_global_load_lds(
          (const __attribute__((address_space(1))) void*)(Ab + (size_t)gr0 * CD + k0 + kk),
          (__attribute__((address_space(3))) void*)(As + wv * 512), 16, 0, 0);
      __builtin_amdgcn_global_load_lds(
          (const __attribute__((address_space(1))) void*)(Ab + (size_t)gr1 * CD + k0 + kk),
          (__attribute__((address_space(3))) void*)(As + 2048 + wv * 512), 16, 0, 0);
      __builtin_amdgcn_global_load_lds(
          (const __attribute__((address_space(1))) void*)(Bb + (size_t)gs0 * CD + k0 + kk),
          (__attribute__((address_space(3))) void*)(Bs + wv * 512), 16, 0, 0);
      __builtin_amdgcn_global_load_lds(
          (const __attribute__((address_space(1))) void*)(Bb + (size_t)gs1 * CD + k0 + kk),
          (__attribute__((address_space(3))) void*)(Bs + 2048 + wv * 512), 16, 0, 0);
      __syncthreads();   // compiler drains vmcnt(0) here -> LDS valid
      bf16x8 af[4], bfr[4];
#pragma unroll
      for (int m = 0; m < 4; ++m) {
        af[m]  = *(const bf16x8*)(As + (wr * 64 + m * 16 + c0) * 32 + q * 8);
        bfr[m] = *(const bf16x8*)(Bs + (wc * 64 + m * 16 + c0) * 32 + q * 8);
      }
#pragma unroll
      for (int m = 0; m < 4; ++m)
#pragma unroll
        for (int nn = 0; nn < 4; ++nn)
          acc[m][nn] = __builtin_amdgcn_mfma_f32_16x16x32_bf16(af[m], bfr[nn], acc[m][nn], 0, 0, 0);
    }
  } else {
    const float* A = f0 + (size_t)n * LD * CD;
    const float* B = f1 + (size_t)n * SD * CD;
    for (int k0 = 0; k0 < CD; k0 += 32) {
      __syncthreads();
#pragma unroll
      for (int i = 0; i < 4; ++i) {
        int e = (i * 256 + t) * 4;
        int row = e >> 5, k = e & 31;
        int gr = min(br + row, LD - 1), gs = min(bs + row, SD - 1);
        f32x4 va = *(const f32x4*)(A + (size_t)gr * CD + k0 + k);
        f32x4 vb = *(const f32x4*)(B + (size_t)gs * CD + k0 + k);
        u16x4 ua = { f2bf(va.x), f2bf(va.y), f2bf(va.z), f2bf(va.w) };
        u16x4 ub = { f2bf(vb.x), f2bf(vb.y), f2bf(vb.z), f2bf(vb.w) };
        *(u16x4*)(As + row * 32 + k) = ua;
        *(u16x4*)(Bs + row * 32 + k) = ub;
      }
      __syncthreads();
      bf16x8 af[4], bfr[4];
#pragma unroll
      for (int m = 0; m < 4; ++m) {
        af[m]  = *(const bf16x8*)(As + (wr * 64 + m * 16 + c0) * 32 + q * 8);
        bfr[m] = *(const bf16x8*)(Bs + (wc * 64 + m * 16 + c0) * 32 + q * 8);
      }
#pragma unroll
      for (int m = 0; m < 4; ++m)
#pragma unroll
        for (int nn = 0; nn < 4; ++nn)
          acc[m][nn] = __builtin_amdgcn_mfma_f32_16x16x32_bf16(af[m], bfr[nn], acc[m][nn], 0, 0, 0);
    }
  }

  // ---- epilogue ----
  const bool u8 = mask_is_u8(m0);
  int grow[16]; bool inrow[16], mrow[16];
#pragma unroll
  for (int m = 0; m < 4; ++m)
#pragma unroll
    for (int i = 0; i < 4; ++i) {
      int idx = m * 4 + i;
      int r = br + wr * 64 + m * 16 + q * 4 + i;
      grow[idx] = r;
      bool inb = r < LD;
      inrow[idx] = inb;
      mrow[idx] = inb && mask_at(m0, n * LD + (inb ? r : 0), u8);
    }
  int gcol[4]; bool incol[4], mcol[4];
#pragma unroll
  for (int nn = 0; nn < 4; ++nn) {
    int c = bs + wc * 64 + nn * 16 + c0;
    gcol[nn] = c;
    bool inb = c < SD;
    incol[nn] = inb;
    mcol[nn] = inb && mask_at(m1, n * SD + (inb ? c : 0), u8);
  }

  if constexpr (PASS == 0) {
    float rpart[16];
#pragma unroll
    for (int i = 0; i < 16; ++i) rpart[i] = 0.f;
    float cpart[4] = {0.f, 0.f, 0.f, 0.f};
#pragma unroll
    for (int m = 0; m < 4; ++m)
#pragma unroll
      for (int nn = 0; nn < 4; ++nn) {
        f32x4 a = acc[m][nn];
#pragma unroll
        for (int i = 0; i < 4; ++i) {
          int idx = m * 4 + i;
          float val = a[i] * SIMSCALE;
          bool v = mrow[idx] && mcol[nn];
          float e = v ? __expf(val) : 0.f;
          rpart[idx] += e;
          cpart[nn] += e;
        }
      }
#pragma unroll
    for (int idx = 0; idx < 16; ++idx) {
      float s = rpart[idx];
      s += __shfl_xor(s, 1); s += __shfl_xor(s, 2);
      s += __shfl_xor(s, 4); s += __shfl_xor(s, 8);
      if (c0 == 0 && inrow[idx]) atomicAdd(&rowsum[n * LD + grow[idx]], s);
    }
#pragma unroll
    for (int nn = 0; nn < 4; ++nn) {
      float s = cpart[nn];
      s += __shfl_xor(s, 16); s += __shfl_xor(s, 32);
      if (q == 0 && incol[nn]) atomicAdd(&colsum[n * SD + gcol[nn]], s);
    }
  } else {
    float rinv[16];
#pragma unroll
    for (int idx = 0; idx < 16; ++idx)
      rinv[idx] = 1.0f / rowsum[n * LD + (inrow[idx] ? grow[idx] : 0)];
    float cinv[4];
#pragma unroll
    for (int nn = 0; nn < 4; ++nn)
      cinv[nn] = 1.0f / colsum[n * SD + (incol[nn] ? gcol[nn] : 0)];

    ull rkey[16];
#pragma unroll
    for (int i = 0; i < 16; ++i) rkey[i] = 0ull;
    float cmax[4] = {0.f, 0.f, 0.f, 0.f};

#pragma unroll
    for (int m = 0; m < 4; ++m)
#pragma unroll
      for (int nn = 0; nn < 4; ++nn) {
        f32x4 a = acc[m][nn];
#pragma unroll
        for (int i = 0; i < 4; ++i) {
          int idx = m * 4 + i;
          float val = a[i] * SIMSCALE;
          bool v = mrow[idx] && mcol[nn];
          float e = v ? __expf(val) : 0.f;
          float Aa = mrow[idx] ? e * rinv[idx] : INVL;  // softmax axis 2
          float Bb = mcol[nn] ? e * cinv[nn]  : INVL;   // softmax axis 1
          float cv = Aa * Bb;
          bool ok = inrow[idx] && incol[nn];
          if (ok) {
            out[((size_t)n * LD + grow[idx]) * SD + gcol[nn]] = cv;
            cmax[nn] = fmaxf(cmax[nn], cv);
            ull key = ((ull)__float_as_uint(cv) << 32) | (unsigned)(~gcol[nn]);
            if (key > rkey[idx]) rkey[idx] = key;       // ties -> smaller col
          }
        }
      }
#pragma unroll
    for (int idx = 0; idx < 16; ++idx) {
      ull key = rkey[idx];
#pragma unroll
      for (int d = 1; d < 16; d <<= 1) {
        ull ok2 = __shfl_xor(key, d);
        key = (ok2 > key) ? ok2 : key;
      }
      if (c0 == 0 && inrow[idx]) atomicMax(&rowbest[n * LD + grow[idx]], key);
    }
#pragma unroll
    for (int nn = 0; nn < 4; ++nn) {
      float s = cmax[nn];
      s = fmaxf(s, __shfl_xor(s, 16));
      s = fmaxf(s, __shfl_xor(s, 32));
      if (q == 0 && incol[nn]) atomicMax(&colmax[n * SD + gcol[nn]], __float_as_uint(s));
    }
  }
}

// Pass C: match extraction (mask_v, j_ids, mconf, mkpts0, mkpts1)
__global__ void final_kernel(const ull* __restrict__ rowbest,
                             const unsigned* __restrict__ colmax,
                             const int* __restrict__ dims,
                             float* __restrict__ out) {
  const int n = blockIdx.y;
  const int l = blockIdx.x * 256 + threadIdx.x;
  if (l >= LD) return;
  ull key = rowbest[(size_t)n * LD + l];
  float rmax = __uint_as_float((unsigned)(key >> 32));
  int j = (int)(~(unsigned)(key & 0xFFFFFFFFull));
  if (j < 0 || j >= SD) j = 0;
  const int hs0 = dims[0 + n], ws0 = dims[2 + n], hs1 = dims[4 + n], ws1 = dims[6 + n];
  const int h = l / W0, w = l % W0;
  const bool v0 = (h >= 2) && (h < hs0 - 2) && (w >= 2) && (w < ws0 - 2);
  const int jh = j / W0, jw = j % W0;
  const bool v1 = (jh >= 2) && (jh < hs1 - 2) && (jw >= 2) && (jw < ws1 - 2);
  const float cmx = __uint_as_float(colmax[(size_t)n * SD + j]);
  const bool mv = (rmax > THRV) && v0 && v1 && (rmax == cmx);
  const int jid = mv ? j : 0;

  const size_t base = (size_t)NB * LD * SD;
  const int NL = NB * LD;
  out[base + (size_t)n * LD + l]                  = mv ? 1.f : 0.f;   // mask_v
  out[base + NL + (size_t)n * LD + l]             = (float)jid;       // j_ids
  out[base + 2 * (size_t)NL + (size_t)n * LD + l] = mv ? rmax : 0.f;  // mconf
  size_t mk0 = base + 3 * (size_t)NL + ((size_t)n * LD + l) * 2;
  out[mk0 + 0] = (float)(w * 8);
  out[mk0 + 1] = (float)(h * 8);
  size_t mk1 = base + 5 * (size_t)NL + ((size_t)n * LD + l) * 2;
  out[mk1 + 0] = (float)((jid % W0) * 8);
  out[mk1 + 1] = (float)((jid / W0) * 8);
}

extern "C" void kernel_launch(void* const* d_in, const int* in_sizes, int n_in,
                              void* d_out, int out_size, void* d_ws, size_t ws_size,
                              hipStream_t stream) {
  (void)in_sizes; (void)n_in; (void)out_size;
  const float* f0 = (const float*)d_in[0];
  const float* f1 = (const float*)d_in[1];
  const void*  m0 = d_in[2];
  const void*  m1 = d_in[3];
  float* out = (float*)d_out;
  char* ws = (char*)d_ws;

  const size_t FB_BYTES = (size_t)NB * LD * CD * 2;        // 4,915,200 per tensor
  const bool gll = ws_size >= 2 * FB_BYTES + 192032;

  unsigned short* fb0 = gll ? (unsigned short*)ws : nullptr;
  unsigned short* fb1 = gll ? (unsigned short*)(ws + FB_BYTES) : nullptr;
  char* sums = gll ? (ws + 2 * FB_BYTES) : ws;

  float* rowsum = (float*)sums;
  float* colsum = (float*)(sums + 38400);
  unsigned* colmax = (unsigned*)(sums + 76800);
  ull* rowbest = (ull*)(sums + 115200);
  int* dims = (int*)(sums + 192000);

  prep_kernel<<<512, 256, 0, stream>>>(f0, f1, m0, m1, fb0, fb1,
                                       (unsigned*)sums, dims, gll ? 1 : 0);
  if (gll) {
    gemm_fused<0, 1><<<dim3(38, 38, 2), 256, 0, stream>>>(
        fb0, fb1, f0, f1, m0, m1, out, rowsum, colsum, colmax, rowbest);
    gemm_fused<1, 1><<<dim3(38, 38, 2), 256, 0, stream>>>(
        fb0, fb1, f0, f1, m0, m1, out, rowsum, colsum, colmax, rowbest);
  } else {
    gemm_fused<0, 0><<<dim3(38, 38, 2), 256, 0, stream>>>(
        fb0, fb1, f0, f1, m0, m1, out, rowsum, colsum, colmax, rowbest);
    gemm_fused<1, 0><<<dim3(38, 38, 2), 256, 0, stream>>>(
        fb0, fb1, f0, f1, m0, m1, out, rowsum, colsum, colmax, rowbest);
  }
  final_kernel<<<dim3(19, 2), 256, 0, stream>>>(rowbest, colmax, dims, out);
}